// Round 3
// baseline (306.815 us; speedup 1.0000x reference)
//
#include <hip/hip_runtime.h>

#define N_TOK 4096
#define DMODEL 1024
#define NEXP 16
#define HDIM 2048
#define CAP 1024

typedef __attribute__((ext_vector_type(8))) short frag8;      // 8 bf16 (4 VGPR) MFMA operand
typedef __attribute__((ext_vector_type(4))) float f32x4;      // MFMA accumulator
typedef __attribute__((ext_vector_type(8))) unsigned short us8;
typedef unsigned short ushortT;

__device__ __forceinline__ unsigned short f2bf(float x) {
  unsigned u = __builtin_bit_cast(unsigned, x);
  u += 0x7fffu + ((u >> 16) & 1u);           // RNE
  return (unsigned short)(u >> 16);
}

__device__ __forceinline__ void load_lds16(const void* g, void* l) {
  __builtin_amdgcn_global_load_lds((const __attribute__((address_space(1))) void*)g,
                                   (__attribute__((address_space(3))) void*)l, 16, 0, 0);
}

// ---------------- gate phase 1: logits -> top2 -> softmax (NO atomics) ----------------
__global__ __launch_bounds__(256) void gate_logits_kernel(
    const float* __restrict__ x, const float* __restrict__ Wg, const float* __restrict__ bg,
    int* __restrict__ a_e, float* __restrict__ a_gate)
{
  int wid = threadIdx.x >> 6, l = threadIdx.x & 63;
  int n = blockIdx.x * 4 + wid;
  const float* xr = x + (size_t)n * DMODEL;
  float acc[NEXP];
#pragma unroll
  for (int e = 0; e < NEXP; ++e) acc[e] = 0.f;
#pragma unroll
  for (int q = 0; q < 4; ++q) {
    float4 xv = *(const float4*)(xr + q * 256 + l * 4);
    const float* wr = Wg + (size_t)(q * 256 + l * 4) * NEXP;
#pragma unroll
    for (int j = 0; j < 4; ++j) {
      float xs = j == 0 ? xv.x : j == 1 ? xv.y : j == 2 ? xv.z : xv.w;
      const float4* w4 = (const float4*)(wr + j * NEXP);
#pragma unroll
      for (int qq = 0; qq < 4; ++qq) {
        float4 w = w4[qq];
        acc[qq*4+0] += xs * w.x; acc[qq*4+1] += xs * w.y;
        acc[qq*4+2] += xs * w.z; acc[qq*4+3] += xs * w.w;
      }
    }
  }
#pragma unroll
  for (int e = 0; e < NEXP; ++e) {
    float v = acc[e];
#pragma unroll
    for (int off = 32; off > 0; off >>= 1) v += __shfl_xor(v, off, 64);
    acc[e] = v + bg[e];
  }
  if (l == 0) {
    int i1 = 0; float v1 = acc[0];
#pragma unroll
    for (int e = 1; e < NEXP; ++e) if (acc[e] > v1) { v1 = acc[e]; i1 = e; }
    int i2 = -1; float v2 = -1e30f;
#pragma unroll
    for (int e = 0; e < NEXP; ++e) if (e != i1 && acc[e] > v2) { v2 = acc[e]; i2 = e; }
    float e2 = __expf(v2 - v1);
    float inv = 1.f / (1.f + e2);
    a_e[n*2] = i1;   a_gate[n*2] = inv;
    a_e[n*2+1] = i2; a_gate[n*2+1] = e2 * inv;
  }
}

// ---------------- gate phase 2: per-expert slot assignment via LDS counter ----------------
__global__ __launch_bounds__(256) void assign_kernel(
    const int* __restrict__ a_e, int* __restrict__ a_slot,
    int* __restrict__ tok_of_slot, int* __restrict__ cnt)
{
  __shared__ int c;
  if (threadIdx.x == 0) c = 0;
  __syncthreads();
  int eid = blockIdx.x;
  for (int j = threadIdx.x; j < N_TOK * 2; j += 256) {
    if (a_e[j] == eid) {
      int p = atomicAdd(&c, 1);
      a_slot[j] = p;
      if (p < CAP) tok_of_slot[eid * CAP + p] = j >> 1;
    }
  }
  __syncthreads();
  if (threadIdx.x == 0) cnt[eid] = c;
}

// ---------------- gather: x rows -> bf16 blocked+swizzled A-layout [e][rt][kt][128][64] ----------------
__global__ __launch_bounds__(256) void gather_kernel(
    const float* __restrict__ x, const int* __restrict__ cnt,
    const int* __restrict__ tok_of_slot, unsigned short* __restrict__ Xe)
{
  int rid = blockIdx.x * 2 + (threadIdx.x >> 7);
  int tl = threadIdx.x & 127;
  int e = rid >> 10, slot = rid & (CAP - 1);
  int c = cnt[e]; if (c > CAP) c = CAP;
  if (slot >= c) return;
  int tok = tok_of_slot[rid];
  const float4* xs = (const float4*)(x + (size_t)tok * DMODEL + tl * 8);
  float4 u = xs[0], v = xs[1];
  us8 p;
  p[0]=f2bf(u.x); p[1]=f2bf(u.y); p[2]=f2bf(u.z); p[3]=f2bf(u.w);
  p[4]=f2bf(v.x); p[5]=f2bf(v.y); p[6]=f2bf(v.z); p[7]=f2bf(v.w);
  int kt = tl >> 3, s = tl & 7;
  int row = slot & 127, rt = slot >> 7;
  size_t off = ((size_t)((e*8 + rt)*16 + kt)) * 8192 + (size_t)row*64 + ((s ^ (row & 7)) << 3);
  *(us8*)&Xe[off] = p;
}

// ---------------- prepack: src f32 [E][R][C] -> dst bf16 blocked logical [C][R] ----------------
__global__ __launch_bounds__(256) void prepack_kernel(
    const float* __restrict__ src, unsigned short* __restrict__ dst, int R, int C)
{
  __shared__ float tr[64 * 133];
  int nrt = C >> 7, nkt = R >> 6;
  int bid = blockIdx.x;
  int e = bid / (nrt * nkt), rem = bid % (nrt * nkt);
  int rt = rem / nkt, kt = rem % nkt;
  int t = threadIdx.x;
  int r0 = kt * 64, c0 = rt * 128;
  const float* sp = src + ((size_t)e * R + r0) * C + c0;
#pragma unroll
  for (int i = 0; i < 8; ++i) {
    int row = i * 8 + (t >> 5), col = (t & 31) * 4;
    float4 v = *(const float4*)(sp + (size_t)row * C + col);
    float* d = &tr[row * 133 + col];
    d[0] = v.x; d[1] = v.y; d[2] = v.z; d[3] = v.w;
  }
  __syncthreads();
  size_t obase = ((size_t)(e * nrt + rt) * nkt + kt) * 8192;
#pragma unroll
  for (int q = 0; q < 4; ++q) {
    int chunk = q * 256 + t;
    int orow = chunk >> 3, sl = chunk & 7;
    us8 p;
#pragma unroll
    for (int j = 0; j < 8; ++j) p[j] = f2bf(tr[(sl*8 + j)*133 + orow]);
    *(us8*)&dst[obase + (size_t)orow*64 + ((sl ^ (orow & 7)) << 3)] = p;
  }
}

// ---------------- grouped GEMM, 256x(NBB*128) tile, 8 waves, 2-phase double-buffer ----------------
// A blocked [e][rt:8][kt:KTB][128][64] pre-swizzled; B blocked [e][ntb:NTB_TOT][kt:KTB][128][64]
template<int KTB, int NTB_TOT, int NBB, bool GELU, bool OUT_BLOCKED>
__global__ __launch_bounds__(512, 2) void gemm2ph_kernel(
    const unsigned short* __restrict__ A, const unsigned short* __restrict__ B,
    void* __restrict__ OutP, const float* __restrict__ bias, const int* __restrict__ cnt)
{
  __shared__ __align__(16) unsigned short smem[(4 + 2 * NBB) * 8192]; // A dbuf 64K + B dbuf
  char* smem_b = (char*)smem;
  constexpr int BBUF = NBB * 16384;       // B bytes per buffer
  int bid = blockIdx.x;
  int e = bid >> 5, rem = bid & 31;
  int mt = rem >> 3, nt = rem & 7;        // 4 mt x 8 nt
  int mcnt = cnt[e]; if (mcnt > CAP) mcnt = CAP;
  if (mt * 256 >= mcnt) return;
  int t = threadIdx.x, l = t & 63, wid = t >> 6;
  int wm = wid >> 2, wn = wid & 3;        // 2M x 4N waves, per-wave 128 x (NBB*32)
  int rA = l & 15, g = l >> 4, r7 = rA & 7;
  int swz0 = (g ^ r7) << 4;               // kh=0 byte slot
  int swz1 = ((g + 4) ^ r7) << 4;         // kh=1
  int e8 = e * 8, mt2 = mt * 2;
  int aOff = wm * 16384 + rA * 128;
  int bOff = (NBB == 2) ? ((wn >> 1) * 16384 + ((wn & 1) * 64 + rA) * 128)
                        : ((wn * 32 + rA) * 128);
  const unsigned short* sa0b = A + (size_t)(e8 + mt2) * KTB * 8192;
  const unsigned short* sb0b = B + (size_t)(e * NTB_TOT + nt * NBB) * KTB * 8192;

  f32x4 acc[8][2 * NBB] = {};

  auto stage = [&](int bv, int kt) {
    const unsigned short* sa0 = sa0b + (size_t)kt * 8192;
    const unsigned short* sa1 = sa0 + (size_t)KTB * 8192;
    char* lA = smem_b + bv * 32768;
    load_lds16(sa0 + t * 8,        lA + wid * 1024);
    load_lds16(sa0 + 4096 + t * 8, lA + 8192 + wid * 1024);
    load_lds16(sa1 + t * 8,        lA + 16384 + wid * 1024);
    load_lds16(sa1 + 4096 + t * 8, lA + 24576 + wid * 1024);
    const unsigned short* sb0 = sb0b + (size_t)kt * 8192;
    char* lB = smem_b + 65536 + bv * BBUF;
    load_lds16(sb0 + t * 8,        lB + wid * 1024);
    load_lds16(sb0 + 4096 + t * 8, lB + 8192 + wid * 1024);
    if (NBB == 2) {
      const unsigned short* sb1 = sb0 + (size_t)KTB * 8192;
      load_lds16(sb1 + t * 8,        lB + 16384 + wid * 1024);
      load_lds16(sb1 + 4096 + t * 8, lB + 24576 + wid * 1024);
    }
  };

  stage(0, 0);
  __syncthreads();                         // drains vmcnt(0): buf0 ready

  int buf = 0;
  for (int kt = 0; kt < KTB; ++kt) {
    if (kt + 1 < KTB) stage(buf ^ 1, kt + 1);   // prefetch next tile (overlaps MFMA below)
    const char* bA = smem_b + buf * 32768 + aOff;
    const char* bB = smem_b + 65536 + buf * BBUF + bOff;
    frag8 bfr[2 * NBB][2];
#pragma unroll
    for (int n16 = 0; n16 < 2 * NBB; ++n16) {
      bfr[n16][0] = *(const frag8*)(bB + n16 * 2048 + swz0);
      bfr[n16][1] = *(const frag8*)(bB + n16 * 2048 + swz1);
    }
    __builtin_amdgcn_s_setprio(1);
#pragma unroll
    for (int m16 = 0; m16 < 8; ++m16) {
      frag8 a0 = *(const frag8*)(bA + m16 * 2048 + swz0);
      frag8 a1 = *(const frag8*)(bA + m16 * 2048 + swz1);
#pragma unroll
      for (int n16 = 0; n16 < 2 * NBB; ++n16) {
        acc[m16][n16] = __builtin_amdgcn_mfma_f32_16x16x32_bf16(a0, bfr[n16][0], acc[m16][n16], 0, 0, 0);
        acc[m16][n16] = __builtin_amdgcn_mfma_f32_16x16x32_bf16(a1, bfr[n16][1], acc[m16][n16], 0, 0, 0);
      }
    }
    __builtin_amdgcn_s_setprio(0);
    __syncthreads();                       // one barrier per K-step; drains prefetch vmcnt
    buf ^= 1;
  }

  if (OUT_BLOCKED) {
    // bias + gelu + f2bf -> per-wave LDS bounce (16KB) -> blocked bf16 out [e][rt8][ktb32][128][64]
    float bv[4];
#pragma unroll
    for (int n16 = 0; n16 < 4; ++n16)
      bv[n16] = bias[e * 2048 + nt * 256 + wn * 64 + n16 * 16 + rA];
    char* wb = smem_b + wid * 16384;
#pragma unroll
    for (int m16 = 0; m16 < 8; ++m16)
#pragma unroll
      for (int n16 = 0; n16 < 2 * NBB; ++n16)
#pragma unroll
        for (int rr = 0; rr < 4; ++rr) {
          float xv = acc[m16][n16][rr] + bv[n16];
          if (GELU) {
            float u = 0.7978845608028654f * (xv + 0.044715f * xv * xv * xv);
            xv = xv / (1.f + __expf(-2.f * u));     // x*sigmoid(2u) == gelu_tanh, no NaN
          }
          int rowl = m16 * 16 + g * 4 + rr;         // 0..127
          int col  = n16 * 16 + rA;                 // 0..63
          *(unsigned short*)(wb + rowl * 128 + (((col >> 3) ^ (rowl & 7)) << 4) + (col & 7) * 2) = f2bf(xv);
        }
    asm volatile("s_waitcnt lgkmcnt(0)" ::: "memory");
    unsigned short* Out = (unsigned short*)OutP;
    size_t ob = ((size_t)(e8 + mt2 + wm) * 32 + nt * 4 + wn) * 8192;
#pragma unroll
    for (int it = 0; it < 16; ++it) {
      int row = it * 8 + (l >> 3), p = l & 7;
      us8 v = *(const us8*)(wb + row * 128 + p * 16);
      *(us8*)&Out[ob + (size_t)row * 64 + p * 8] = v;
    }
  } else {
    float* Out = (float*)OutP;              // linear f32 [e][CAP][1024]
    float bv[2];
#pragma unroll
    for (int n16 = 0; n16 < 2; ++n16)
      bv[n16] = bias[e * 1024 + nt * 128 + wn * 32 + n16 * 16 + rA];
#pragma unroll
    for (int m16 = 0; m16 < 8; ++m16)
#pragma unroll
      for (int n16 = 0; n16 < 2 * NBB; ++n16) {
        int col = nt * 128 + wn * 32 + n16 * 16 + rA;
#pragma unroll
        for (int rr = 0; rr < 4; ++rr) {
          int row = mt * 256 + wm * 128 + m16 * 16 + g * 4 + rr;
          Out[(size_t)(e * CAP + row) * 1024 + col] = acc[m16][n16][rr] + bv[n16];
        }
      }
  }
}

// ---------------- combine: out[n] = g0*ye[e0][s0] + g1*ye[e1][s1] ----------------
__global__ __launch_bounds__(256) void combine_kernel(
    const float* __restrict__ ye, const int* __restrict__ a_e, const int* __restrict__ a_slot,
    const float* __restrict__ a_gate, float* __restrict__ out)
{
  int n = blockIdx.x, t = threadIdx.x;
  int e0 = a_e[n*2], e1 = a_e[n*2+1];
  int s0 = a_slot[n*2], s1 = a_slot[n*2+1];
  float g0 = a_gate[n*2], g1 = a_gate[n*2+1];
  float rx = 0.f, ry = 0.f, rz = 0.f, rw = 0.f;
  if (s0 < CAP) {
    float4 v = *(const float4*)&ye[(size_t)(e0*CAP + s0)*DMODEL + t*4];
    rx += g0*v.x; ry += g0*v.y; rz += g0*v.z; rw += g0*v.w;
  }
  if (s1 < CAP) {
    float4 v = *(const float4*)&ye[(size_t)(e1*CAP + s1)*DMODEL + t*4];
    rx += g1*v.x; ry += g1*v.y; rz += g1*v.z; rw += g1*v.w;
  }
  float4 o; o.x = rx; o.y = ry; o.z = rz; o.w = rw;
  *(float4*)&out[(size_t)n*DMODEL + t*4] = o;
}

extern "C" void kernel_launch(void* const* d_in, const int* in_sizes, int n_in,
                              void* d_out, int out_size, void* d_ws, size_t ws_size,
                              hipStream_t stream) {
  const float* x  = (const float*)d_in[0];
  const float* Wg = (const float*)d_in[1];
  const float* bg = (const float*)d_in[2];
  const float* W1 = (const float*)d_in[3];
  const float* b1 = (const float*)d_in[4];
  const float* W2 = (const float*)d_in[5];
  const float* b2 = (const float*)d_in[6];
  float* out = (float*)d_out;
  char* ws = (char*)d_ws;

  // workspace layout (ye overlays W1T: W1T dead after gemm1) — total ~235MB
  unsigned short* W1T = (unsigned short*)(ws);                 // 67,108,864 B
  unsigned short* W2T = (unsigned short*)(ws + 67108864);      // 67,108,864 B
  unsigned short* Xe  = (unsigned short*)(ws + 134217728);     // 33,554,432 B
  unsigned short* hB  = (unsigned short*)(ws + 167772160);     // 67,108,864 B
  float* ye           = (float*)(ws);                          // 67,108,864 B (overlay)
  int* cnt            = (int*)(ws + 234881024);                // 64 B
  int* tok            = (int*)(ws + 234881088);                // 65,536 B
  int* a_e            = (int*)(ws + 234946624);                // 32,768 B
  int* a_slot         = (int*)(ws + 234979392);                // 32,768 B
  float* a_gate       = (float*)(ws + 235012160);              // 32,768 B

  // W2 prepack first, W1 last -> W1T is L3-hot when gemm1 runs
  prepack_kernel<<<4096, 256, 0, stream>>>(W2, W2T, HDIM, DMODEL);   // W2T logical [D][H]
  prepack_kernel<<<4096, 256, 0, stream>>>(W1, W1T, DMODEL, HDIM);   // W1T logical [H][D]
  gate_logits_kernel<<<1024, 256, 0, stream>>>(x, Wg, bg, a_e, a_gate);
  assign_kernel<<<16, 256, 0, stream>>>(a_e, a_slot, tok, cnt);
  gather_kernel<<<8192, 256, 0, stream>>>(x, cnt, tok, Xe);
  // gemm1: [8192,1024]x[1024,2048] grouped; 256x256 tile; out blocked bf16 + gelu
  gemm2ph_kernel<16, 16, 2, true,  true ><<<512, 512, 0, stream>>>(Xe, W1T, (void*)hB, b1, cnt);
  // gemm2: [8192,2048]x[2048,1024] grouped; 256x128 tile; out linear f32
  gemm2ph_kernel<32, 8,  1, false, false><<<512, 512, 0, stream>>>(hB, W2T, (void*)ye, b2, cnt);
  combine_kernel<<<4096, 256, 0, stream>>>(ye, a_e, a_slot, a_gate, out);
}